// Round 1
// baseline (2945.991 us; speedup 1.0000x reference)
//
#include <hip/hip_runtime.h>

typedef float  f32x4 __attribute__((ext_vector_type(4)));
typedef short  s16x8 __attribute__((ext_vector_type(8)));

#define BB 256      // batch
#define TT 32       // seq len
#define DD 1024
#define HH 8
#define HDIM 128
#define LL 3
#define FF 2048
#define SSRC 64

__device__ __forceinline__ float b2f(short s) {
    return __uint_as_float(((unsigned)(unsigned short)s) << 16);
}
__device__ __forceinline__ short f2b(float f) {
    unsigned u = __float_as_uint(f);
    u = u + 0x7fffu + ((u >> 16) & 1u);
    return (short)(u >> 16);
}

// ---------------------------------------------------------------------------
// Generic bf16 MFMA GEMM: C[M,N] = A[M,K] * Bt[N,K]^T (+bias) with epilogues.
// 128x128 tile, 4 waves (2x2 of 64x64), BK=64, reg-staged LDS.
// epi: 0 Cb=bf16(v)  1 Cf=v  2 Cb=bf16(v+sym2[sid[row]]+pe[row&31])
//      3 Cb=bf16(relu v)  4 Cf=v+res[idx]  5 Cf=v, Cb=bf16(v)
// ---------------------------------------------------------------------------
__global__ __launch_bounds__(256) void gemm_bt(
    const short* __restrict__ A, const short* __restrict__ Bt,
    const float* __restrict__ bias,
    float* __restrict__ Cf, short* __restrict__ Cb,
    const short* __restrict__ res,
    const float* __restrict__ sym2, const int* __restrict__ sid,
    const float* __restrict__ pe,
    int M, int N, int K, int epi)
{
    __shared__ short As[128 * 64];
    __shared__ short Bs[128 * 64];
    const int tid  = threadIdx.x;
    const int lane = tid & 63;
    const int wave = tid >> 6;
    const int m0 = blockIdx.y * 128, n0 = blockIdx.x * 128;
    const int wm = (wave >> 1) * 64, wn = (wave & 1) * 64;
    const int l15 = lane & 15, l4 = lane >> 4;

    f32x4 acc[4][4];
#pragma unroll
    for (int m = 0; m < 4; m++)
#pragma unroll
        for (int n = 0; n < 4; n++)
#pragma unroll
            for (int j = 0; j < 4; j++) acc[m][n][j] = 0.f;

    const int rB = tid >> 3;          // staging row base (0..31)
    const int cS = (tid & 7) * 8;     // staging col (0..56)

    for (int k0 = 0; k0 < K; k0 += 64) {
        s16x8 av[4], bv[4];
#pragma unroll
        for (int i = 0; i < 4; i++) {
            int r = i * 32 + rB;
            av[i] = *(const s16x8*)(A  + (size_t)(m0 + r) * K + k0 + cS);
            bv[i] = *(const s16x8*)(Bt + (size_t)(n0 + r) * K + k0 + cS);
        }
        __syncthreads();
#pragma unroll
        for (int i = 0; i < 4; i++) {
            int r = i * 32 + rB;
            *(s16x8*)(As + r * 64 + cS) = av[i];
            *(s16x8*)(Bs + r * 64 + cS) = bv[i];
        }
        __syncthreads();
#pragma unroll
        for (int kk = 0; kk < 64; kk += 32) {
            s16x8 af[4], bfv[4];
#pragma unroll
            for (int m = 0; m < 4; m++)
                af[m] = *(const s16x8*)(As + (wm + m * 16 + l15) * 64 + kk + l4 * 8);
#pragma unroll
            for (int n = 0; n < 4; n++)
                bfv[n] = *(const s16x8*)(Bs + (wn + n * 16 + l15) * 64 + kk + l4 * 8);
#pragma unroll
            for (int m = 0; m < 4; m++)
#pragma unroll
                for (int n = 0; n < 4; n++)
                    acc[m][n] = __builtin_amdgcn_mfma_f32_16x16x32_bf16(
                        af[m], bfv[n], acc[m][n], 0, 0, 0);
        }
    }

#pragma unroll
    for (int m = 0; m < 4; m++) {
#pragma unroll
        for (int n = 0; n < 4; n++) {
#pragma unroll
            for (int j = 0; j < 4; j++) {
                int row = m0 + wm + m * 16 + l4 * 4 + j;
                int col = n0 + wn + n * 16 + l15;
                float v = acc[m][n][j];
                if (bias) v += bias[col];
                size_t idx = (size_t)row * N + col;
                if (epi == 0) {
                    Cb[idx] = f2b(v);
                } else if (epi == 1) {
                    Cf[idx] = v;
                } else if (epi == 2) {
                    v += sym2[(size_t)sid[row] * 1024 + col] + pe[(size_t)(row & 31) * 1024 + col];
                    Cb[idx] = f2b(v);
                } else if (epi == 3) {
                    Cb[idx] = f2b(fmaxf(v, 0.f));
                } else if (epi == 4) {
                    Cf[idx] = v + b2f(res[idx]);
                } else {
                    Cf[idx] = v; Cb[idx] = f2b(v);
                }
            }
        }
    }
}

// ---------------------------------------------------------------------------
// Self attention: one block per (b,h). Tq=Tk=32, HD=128.
// qkv: [8192, 3072] bf16 (q|k|v). out: [8192,1024] bf16.
// ---------------------------------------------------------------------------
__global__ __launch_bounds__(256) void attn_self(const short* __restrict__ qkv,
                                                 short* __restrict__ o)
{
    const int b = blockIdx.x >> 3, h = blockIdx.x & 7;
    __shared__ short Q[32 * 128], Kk[32 * 128], Vv[32 * 128];
    __shared__ float S[32 * 32];
    const int tid = threadIdx.x;
    const size_t base = (size_t)b * 32 * 3072 + h * 128;
    for (int i = tid; i < 512; i += 256) {
        int r = i >> 4, c = (i & 15) * 8;
        size_t g = base + (size_t)r * 3072 + c;
        *(s16x8*)(Q  + r * 128 + c) = *(const s16x8*)(qkv + g);
        *(s16x8*)(Kk + r * 128 + c) = *(const s16x8*)(qkv + g + 1024);
        *(s16x8*)(Vv + r * 128 + c) = *(const s16x8*)(qkv + g + 2048);
    }
    __syncthreads();
    for (int i = tid; i < 1024; i += 256) {
        int r = i >> 5, c = i & 31;
        float s = 0.f;
        for (int d8 = 0; d8 < 16; d8++) {
            s16x8 qa = *(const s16x8*)(Q  + r * 128 + d8 * 8);
            s16x8 ka = *(const s16x8*)(Kk + c * 128 + d8 * 8);
#pragma unroll
            for (int j = 0; j < 8; j++) s += b2f(qa[j]) * b2f(ka[j]);
        }
        S[i] = s * 0.088388347648318447f;
    }
    __syncthreads();
    if (tid < 32) {
        float mx = -1e30f;
        for (int c = 0; c < 32; c++) mx = fmaxf(mx, S[tid * 32 + c]);
        float sum = 0.f;
        for (int c = 0; c < 32; c++) { float p = __expf(S[tid * 32 + c] - mx); S[tid * 32 + c] = p; sum += p; }
        float inv = 1.f / sum;
        for (int c = 0; c < 32; c++) S[tid * 32 + c] *= inv;
    }
    __syncthreads();
    for (int i = tid; i < 4096; i += 256) {
        int r = i >> 7, d = i & 127;
        float a = 0.f;
        for (int c = 0; c < 32; c++) a += S[r * 32 + c] * b2f(Vv[c * 128 + d]);
        o[(size_t)(b * 32 + r) * 1024 + h * 128 + d] = f2b(a);
    }
}

// Cross attention: Tq=32, Tk=64, key-padding mask (1 = padded).
__global__ __launch_bounds__(256) void attn_cross(const short* __restrict__ q_,
                                                  const short* __restrict__ ckv,
                                                  const int* __restrict__ mask,
                                                  short* __restrict__ o)
{
    const int b = blockIdx.x >> 3, h = blockIdx.x & 7;
    __shared__ short Q[32 * 128], Kk[64 * 128], Vv[64 * 128];
    __shared__ float S[32 * 64];
    const int tid = threadIdx.x;
    for (int i = tid; i < 512; i += 256) {
        int r = i >> 4, c = (i & 15) * 8;
        *(s16x8*)(Q + r * 128 + c) = *(const s16x8*)(q_ + (size_t)(b * 32 + r) * 1024 + h * 128 + c);
    }
    for (int i = tid; i < 1024; i += 256) {
        int r = i >> 4, c = (i & 15) * 8;
        size_t g = (size_t)(b * 64 + r) * 2048 + h * 128 + c;
        *(s16x8*)(Kk + r * 128 + c) = *(const s16x8*)(ckv + g);
        *(s16x8*)(Vv + r * 128 + c) = *(const s16x8*)(ckv + g + 1024);
    }
    __syncthreads();
    for (int i = tid; i < 2048; i += 256) {
        int r = i >> 6, c = i & 63;
        float s = 0.f;
        for (int d8 = 0; d8 < 16; d8++) {
            s16x8 qa = *(const s16x8*)(Q  + r * 128 + d8 * 8);
            s16x8 ka = *(const s16x8*)(Kk + c * 128 + d8 * 8);
#pragma unroll
            for (int j = 0; j < 8; j++) s += b2f(qa[j]) * b2f(ka[j]);
        }
        s *= 0.088388347648318447f;
        if (mask[b * 64 + c] != 0) s = -1e9f;
        S[i] = s;
    }
    __syncthreads();
    if (tid < 32) {
        float mx = -1e30f;
        for (int c = 0; c < 64; c++) mx = fmaxf(mx, S[tid * 64 + c]);
        float sum = 0.f;
        for (int c = 0; c < 64; c++) { float p = __expf(S[tid * 64 + c] - mx); S[tid * 64 + c] = p; sum += p; }
        float inv = 1.f / sum;
        for (int c = 0; c < 64; c++) S[tid * 64 + c] *= inv;
    }
    __syncthreads();
    for (int i = tid; i < 4096; i += 256) {
        int r = i >> 7, d = i & 127;
        float a = 0.f;
        for (int c = 0; c < 64; c++) a += S[r * 64 + c] * b2f(Vv[c * 128 + d]);
        o[(size_t)(b * 32 + r) * 1024 + h * 128 + d] = f2b(a);
    }
}

// Row LayerNorm over D=1024 (f32 in -> bf16 out), one block per row.
__global__ __launch_bounds__(256) void ln_rows(const float* __restrict__ X,
                                               short* __restrict__ Y,
                                               const float* __restrict__ g,
                                               const float* __restrict__ bt)
{
    const int row = blockIdx.x, tid = threadIdx.x;
    const float4 v = *(const float4*)(X + (size_t)row * 1024 + tid * 4);
    float s = v.x + v.y + v.z + v.w;
    float q = v.x * v.x + v.y * v.y + v.z * v.z + v.w * v.w;
#pragma unroll
    for (int o = 1; o < 64; o <<= 1) { s += __shfl_xor(s, o); q += __shfl_xor(q, o); }
    __shared__ float ls[4], lq[4];
    if ((tid & 63) == 0) { ls[tid >> 6] = s; lq[tid >> 6] = q; }
    __syncthreads();
    s = ls[0] + ls[1] + ls[2] + ls[3];
    q = lq[0] + lq[1] + lq[2] + lq[3];
    const float mean = s * 0.0009765625f;
    const float var  = q * 0.0009765625f - mean * mean;
    const float rs = rsqrtf(var + 1e-5f);
#pragma unroll
    for (int j = 0; j < 4; j++) {
        int c = tid * 4 + j;
        float xv = (((const float*)&v)[j] - mean) * rs * g[c] + bt[c];
        Y[(size_t)row * 1024 + c] = f2b(xv);
    }
}

// f32 -> bf16 flat convert (n multiple of 8)
__global__ __launch_bounds__(256) void convf2b(const float* __restrict__ s,
                                               short* __restrict__ d, int n)
{
    int i = (blockIdx.x * 256 + threadIdx.x) * 8;
    if (i < n) {
        float4 a = *(const float4*)(s + i);
        float4 b = *(const float4*)(s + i + 4);
        s16x8 o;
        o[0] = f2b(a.x); o[1] = f2b(a.y); o[2] = f2b(a.z); o[3] = f2b(a.w);
        o[4] = f2b(b.x); o[5] = f2b(b.y); o[6] = f2b(b.z); o[7] = f2b(b.w);
        *(s16x8*)(d + i) = o;
    }
}

// f32 [R,C] -> bf16 [C,R] transpose-convert, 32x32 tiles
__global__ __launch_bounds__(256) void transpose_conv(const float* __restrict__ src,
                                                      short* __restrict__ dst,
                                                      int R, int C)
{
    __shared__ float t[32][33];
    int c0 = blockIdx.x * 32, r0 = blockIdx.y * 32;
    int tx = threadIdx.x & 31, ty = threadIdx.x >> 5;
#pragma unroll
    for (int i = 0; i < 32; i += 8) t[ty + i][tx] = src[(size_t)(r0 + ty + i) * C + c0 + tx];
    __syncthreads();
#pragma unroll
    for (int i = 0; i < 32; i += 8) dst[(size_t)(c0 + ty + i) * R + r0 + tx] = f2b(t[tx][ty + i]);
}

// pad rows to 128 (cols=1024), zero-fill beyond src_rows
__global__ __launch_bounds__(256) void pad_conv(const float* __restrict__ s,
                                                short* __restrict__ d, int src_rows)
{
    int i = blockIdx.x * 256 + threadIdx.x;      // 128*1024 total
    int r = i >> 10;
    d[i] = (r < src_rows) ? f2b(s[i]) : (short)0;
}

// positional encoding table [32,1024]
__global__ __launch_bounds__(256) void pe_build(float* __restrict__ pe)
{
    int i = blockIdx.x * 256 + threadIdx.x;      // 32768 total
    int t = i >> 10, d = i & 1023;
    int de = d & ~1;
    float ang = (float)t * expf((float)de * (-9.2103403719761836f / 1024.f));
    pe[i] = (d & 1) ? cosf(ang) : sinf(ang);
}

// gather last decode position: xlast[b] = x[b*32+31]
__global__ __launch_bounds__(256) void gather_last(const short* __restrict__ x,
                                                   short* __restrict__ xlast)
{
    int i = blockIdx.x * 256 + threadIdx.x;      // 256*1024
    int b = i >> 10, d = i & 1023;
    xlast[i] = x[((size_t)(b * 32 + 31) << 10) + d];
}

// Final routed heads -> nll[b]. One wave per batch element.
__global__ __launch_bounds__(64) void head_final(
    const float* __restrict__ logits_a,
    const float* __restrict__ enc_col_f, const short* __restrict__ yc,
    const float* __restrict__ enc_tab_f, const short* __restrict__ yt,
    const float* __restrict__ outf,
    const float* __restrict__ col_b, const float* __restrict__ tab_b,
    const int* __restrict__ view, const int* __restrict__ ga,
    const int* __restrict__ gc, const int* __restrict__ gt,
    float* __restrict__ nll)
{
    const int b = blockIdx.x, lane = threadIdx.x;
    const int vt = view[b];
    if (vt == 0) {
        float x = logits_a[(size_t)b * 128 + lane];   // 64 real action logits
        float mx = x;
#pragma unroll
        for (int o = 1; o < 64; o <<= 1) mx = fmaxf(mx, __shfl_xor(mx, o));
        float sum = __expf(x - mx);
#pragma unroll
        for (int o = 1; o < 64; o <<= 1) sum += __shfl_xor(sum, o);
        float lse = mx + logf(sum);
        float gl = __shfl(x, ga[b]);
        if (lane == 0) nll[b] = lse - gl;
    } else {
        const int nit = (vt == 1) ? 32 : 16;
        const float* enc = (vt == 1) ? (enc_col_f + (size_t)b * 32 * 1024)
                                     : (enc_tab_f + (size_t)b * 16 * 1024);
        const short* y   = (vt == 1) ? (yc + (size_t)b * 1024) : (yt + (size_t)b * 1024);
        const float* bb  = (vt == 1) ? col_b : tab_b;
        float bc = 0.f;
        for (int i = lane; i < 1024; i += 64) bc += bb[i] * outf[(size_t)b * 1024 + i];
#pragma unroll
        for (int o = 1; o < 64; o <<= 1) bc += __shfl_xor(bc, o);
        float logit = -1e30f;
        if (lane < nit) {
            float s = bc;
            const float* er = enc + (size_t)lane * 1024;
            for (int d8 = 0; d8 < 128; d8++) {
                s16x8 yv = *(const s16x8*)(y + d8 * 8);
                float4 e0 = *(const float4*)(er + d8 * 8);
                float4 e1 = *(const float4*)(er + d8 * 8 + 4);
                s += e0.x * b2f(yv[0]) + e0.y * b2f(yv[1]) + e0.z * b2f(yv[2]) + e0.w * b2f(yv[3])
                   + e1.x * b2f(yv[4]) + e1.y * b2f(yv[5]) + e1.z * b2f(yv[6]) + e1.w * b2f(yv[7]);
            }
            logit = s;
        }
        float mx = logit;
#pragma unroll
        for (int o = 1; o < 64; o <<= 1) mx = fmaxf(mx, __shfl_xor(mx, o));
        float sum = (lane < nit) ? __expf(logit - mx) : 0.f;
#pragma unroll
        for (int o = 1; o < 64; o <<= 1) sum += __shfl_xor(sum, o);
        float lse = mx + logf(sum);
        int g = (vt == 1) ? gc[b] : gt[b];
        float gl = __shfl(logit, g);
        if (lane == 0) nll[b] = lse - gl;
    }
}

// ---------------------------------------------------------------------------
extern "C" void kernel_launch(void* const* d_in, const int* in_sizes, int n_in,
                              void* d_out, int out_size, void* d_ws, size_t ws_size,
                              hipStream_t stream)
{
    const float* pa_f     = (const float*)d_in[0];
    const float* src_f    = (const float*)d_in[1];
    const float* colenc_f = (const float*)d_in[2];
    const float* tabenc_f = (const float*)d_in[3];
    const int*   src_mask = (const int*)d_in[4];
    const int*   sym_ids  = (const int*)d_in[5];
    const int*   view     = (const int*)d_in[6];
    const int*   gold_a   = (const int*)d_in[7];
    const int*   gold_c   = (const int*)d_in[8];
    const int*   gold_t   = (const int*)d_in[9];
    const float* sym_emb  = (const float*)d_in[10];
    const float* act_emb  = (const float*)d_in[11];
    const float* Aaff_w   = (const float*)d_in[12];
    const float* Aaff_b   = (const float*)d_in[13];
    const float* Saff_w   = (const float*)d_in[14];
    const float* Saff_b   = (const float*)d_in[15];
    const float* Caff_w   = (const float*)d_in[16];
    const float* Caff_b   = (const float*)d_in[17];
    const float* Taff_w   = (const float*)d_in[18];
    const float* Taff_b   = (const float*)d_in[19];
    const float* tgt_w    = (const float*)d_in[20];
    const float* tgt_b    = (const float*)d_in[21];
    const float* outw     = (const float*)d_in[22];
    const float* outbias  = (const float*)d_in[23];
    const float* self_w   = (const float*)d_in[24];
    const float* self_b   = (const float*)d_in[25];
    const float* cross_w  = (const float*)d_in[26];
    const float* cross_b  = (const float*)d_in[27];
    const float* f1w      = (const float*)d_in[28];
    const float* f1b      = (const float*)d_in[29];
    const float* f2w      = (const float*)d_in[30];
    const float* f2bb     = (const float*)d_in[31];
    const float* lng      = (const float*)d_in[32];
    const float* lnbt     = (const float*)d_in[33];
    float* nll = (float*)d_out;

    char* ws = (char*)d_ws;
    size_t off = 0;
    auto alloc = [&](size_t bytes) -> char* {
        off = (off + 255) & ~(size_t)255;
        char* p = ws + off; off += bytes; return p;
    };

    // bf16 transposed weights
    short* WAaff = (short*)alloc((size_t)1024 * 1024 * 2);
    short* WSaff = (short*)alloc((size_t)1024 * 1024 * 2);
    short* Wtop  = (short*)alloc((size_t)1024 * 1024 * 2);
    short* Wbot  = (short*)alloc((size_t)1024 * 1024 * 2);
    short* Wout  = (short*)alloc((size_t)1024 * 1024 * 2);
    short* Wcol  = (short*)alloc((size_t)1024 * 1024 * 2);
    short* Wtab  = (short*)alloc((size_t)1024 * 1024 * 2);
    short *Wqkv[3], *Wso[3], *Wcq[3], *Wckv[3], *Wco[3], *Wf1[3], *Wf2[3];
    for (int l = 0; l < 3; l++) {
        Wqkv[l] = (short*)alloc((size_t)3072 * 1024 * 2);
        Wso[l]  = (short*)alloc((size_t)1024 * 1024 * 2);
        Wcq[l]  = (short*)alloc((size_t)1024 * 1024 * 2);
        Wckv[l] = (short*)alloc((size_t)2048 * 1024 * 2);
        Wco[l]  = (short*)alloc((size_t)1024 * 1024 * 2);
        Wf1[l]  = (short*)alloc((size_t)2048 * 1024 * 2);
        Wf2[l]  = (short*)alloc((size_t)2048 * 1024 * 2);
    }
    // activations
    short* src_bf   = (short*)alloc((size_t)16384 * 1024 * 2);
    short* sym_pad  = (short*)alloc((size_t)128 * 1024 * 2);
    short* act_pad  = (short*)alloc((size_t)128 * 1024 * 2);
    short* sa_out   = (short*)alloc((size_t)128 * 1024 * 2);
    float* sym2     = (float*)alloc((size_t)128 * 1024 * 4);
    float* pe       = (float*)alloc((size_t)32 * 1024 * 4);
    short* tgt_a    = (short*)alloc((size_t)8192 * 1024 * 2);   // later reused as attn out
    short* x_bf     = (short*)alloc((size_t)8192 * 1024 * 2);
    float* tmp      = (float*)alloc((size_t)8192 * 1024 * 4);   // pre-LN sums; aliases pa_bf & cq
    short* arena    = (short*)alloc((size_t)16384 * 2048 * 2);  // qkv / ckv / ffn-h
    short* xlast    = (short*)alloc((size_t)256 * 1024 * 2);
    float* outf     = (float*)alloc((size_t)256 * 1024 * 4);
    short* outb16   = (short*)alloc((size_t)256 * 1024 * 2);
    short* srca     = (short*)alloc((size_t)128 * 1024 * 2);
    float* logits_a = (float*)alloc((size_t)256 * 128 * 4);
    short* ycb      = (short*)alloc((size_t)256 * 1024 * 2);
    short* ytb      = (short*)alloc((size_t)256 * 1024 * 2);

    short* pa_bf = (short*)tmp;   // alias: dead before tmp first written
    short* cq    = (short*)tmp;   // alias: live only between LN1 and cross o-proj
    short* attn  = tgt_a;         // alias: tgt_a dead once x is built

    const dim3 BLK(256);
    auto conv = [&](const float* s, short* d, size_t n) {
        convf2b<<<dim3((unsigned)(n / 8 / 256)), BLK, 0, stream>>>(s, d, (int)n);
    };
    auto trans = [&](const float* s, short* d, int R, int C) {
        transpose_conv<<<dim3(C / 32, R / 32), BLK, 0, stream>>>(s, d, R, C);
    };
    auto gemm = [&](const short* A, const short* Bt, const float* bias,
                    float* Cf, short* Cb, const short* res,
                    const float* sy, const int* si, const float* pp,
                    int M, int N, int K, int epi) {
        gemm_bt<<<dim3(N / 128, M / 128), BLK, 0, stream>>>(
            A, Bt, bias, Cf, Cb, res, sy, si, pp, M, N, K, epi);
    };

    // ---- phase 0: conversions -------------------------------------------
    pe_build<<<dim3(128), BLK, 0, stream>>>(pe);
    conv(pa_f, pa_bf, (size_t)8192 * 1024);
    conv(src_f, src_bf, (size_t)16384 * 1024);
    conv(Caff_w, Wcol, (size_t)1024 * 1024);
    conv(Taff_w, Wtab, (size_t)1024 * 1024);
    pad_conv<<<dim3(512), BLK, 0, stream>>>(sym_emb, sym_pad, 32);
    pad_conv<<<dim3(512), BLK, 0, stream>>>(act_emb, act_pad, 64);
    trans(Aaff_w, WAaff, 1024, 1024);
    trans(Saff_w, WSaff, 1024, 1024);
    trans(tgt_w, Wtop, 1024, 1024);
    trans(tgt_w + (size_t)1024 * 1024, Wbot, 1024, 1024);
    trans(outw, Wout, 1024, 1024);
    for (int l = 0; l < 3; l++) {
        for (int j = 0; j < 3; j++)
            trans(self_w + (size_t)(l * 4 + j) * 1048576, Wqkv[l] + (size_t)j * 1048576, 1024, 1024);
        trans(self_w + (size_t)(l * 4 + 3) * 1048576, Wso[l], 1024, 1024);
        trans(cross_w + (size_t)(l * 4 + 0) * 1048576, Wcq[l], 1024, 1024);
        trans(cross_w + (size_t)(l * 4 + 1) * 1048576, Wckv[l], 1024, 1024);
        trans(cross_w + (size_t)(l * 4 + 2) * 1048576, Wckv[l] + (size_t)1048576, 1024, 1024);
        trans(cross_w + (size_t)(l * 4 + 3) * 1048576, Wco[l], 1024, 1024);
        trans(f1w + (size_t)l * 2097152, Wf1[l], 1024, 2048);
        trans(f2w + (size_t)l * 2097152, Wf2[l], 2048, 1024);
    }

    // ---- phase 1: embeddings --------------------------------------------
    // sa_out = sym_emb_pad @ Saff + Sb   [128,1024]
    gemm(sym_pad, WSaff, Saff_b, nullptr, sa_out, nullptr, nullptr, nullptr, nullptr,
         128, 1024, 1024, 0);
    // sym2 = sa_out @ Wbot               [128,1024] f32
    gemm(sa_out, Wbot, nullptr, sym2, nullptr, nullptr, nullptr, nullptr, nullptr,
         128, 1024, 1024, 1);
    // tgt_a = pa @ Aaff + Ab             [8192,1024]
    gemm(pa_bf, WAaff, Aaff_b, nullptr, tgt_a, nullptr, nullptr, nullptr, nullptr,
         8192, 1024, 1024, 0);
    // x = tgt_a @ Wtop + tgt_b + sym2[sid] + pe
    gemm(tgt_a, Wtop, tgt_b, nullptr, x_bf, nullptr, sym2, sym_ids, pe,
         8192, 1024, 1024, 2);

    // ---- phase 2: decoder layers ----------------------------------------
    for (int l = 0; l < 3; l++) {
        const float* sb = self_b + (size_t)l * 4096;
        const float* cb = cross_b + (size_t)l * 4096;
        // qkv
        gemm(x_bf, Wqkv[l], sb, nullptr, arena, nullptr, nullptr, nullptr, nullptr,
             8192, 3072, 1024, 0);
        attn_self<<<dim3(2048), BLK, 0, stream>>>(arena, attn);
        gemm(attn, Wso[l], sb + 3072, tmp, nullptr, x_bf, nullptr, nullptr, nullptr,
             8192, 1024, 1024, 4);
        ln_rows<<<dim3(8192), BLK, 0, stream>>>(tmp, x_bf,
            lng + (size_t)(l * 3 + 0) * 1024, lnbt + (size_t)(l * 3 + 0) * 1024);
        // cross
        gemm(x_bf, Wcq[l], cb, nullptr, cq, nullptr, nullptr, nullptr, nullptr,
             8192, 1024, 1024, 0);
        gemm(src_bf, Wckv[l], cb + 1024, nullptr, arena, nullptr, nullptr, nullptr, nullptr,
             16384, 2048, 1024, 0);
        attn_cross<<<dim3(2048), BLK, 0, stream>>>(cq, arena, src_mask, attn);
        gemm(attn, Wco[l], cb + 3072, tmp, nullptr, x_bf, nullptr, nullptr, nullptr,
             8192, 1024, 1024, 4);
        ln_rows<<<dim3(8192), BLK, 0, stream>>>(tmp, x_bf,
            lng + (size_t)(l * 3 + 1) * 1024, lnbt + (size_t)(l * 3 + 1) * 1024);
        // ffn
        gemm(x_bf, Wf1[l], f1b + (size_t)l * 2048, nullptr, arena, nullptr, nullptr, nullptr, nullptr,
             8192, 2048, 1024, 3);
        gemm(arena, Wf2[l], f2bb + (size_t)l * 1024, tmp, nullptr, x_bf, nullptr, nullptr, nullptr,
             8192, 1024, 2048, 4);
        ln_rows<<<dim3(8192), BLK, 0, stream>>>(tmp, x_bf,
            lng + (size_t)(l * 3 + 2) * 1024, lnbt + (size_t)(l * 3 + 2) * 1024);
    }

    // ---- phase 3: heads --------------------------------------------------
    gather_last<<<dim3(1024), BLK, 0, stream>>>(x_bf, xlast);
    gemm(xlast, Wout, outbias, outf, outb16, nullptr, nullptr, nullptr, nullptr,
         256, 1024, 1024, 5);
    gemm(act_pad, WAaff, Aaff_b, nullptr, srca, nullptr, nullptr, nullptr, nullptr,
         128, 1024, 1024, 0);
    gemm(outb16, srca, nullptr, logits_a, nullptr, nullptr, nullptr, nullptr, nullptr,
         256, 128, 1024, 1);
    gemm(outb16, Wcol, nullptr, nullptr, ycb, nullptr, nullptr, nullptr, nullptr,
         256, 1024, 1024, 0);
    gemm(outb16, Wtab, nullptr, nullptr, ytb, nullptr, nullptr, nullptr, nullptr,
         256, 1024, 1024, 0);
    head_final<<<dim3(256), dim3(64), 0, stream>>>(
        logits_a, colenc_f, ycb, tabenc_f, ytb, outf,
        Caff_b, Taff_b, view, gold_a, gold_c, gold_t, nll);
}